// Round 1
// baseline (343.732 us; speedup 1.0000x reference)
//
#include <hip/hip_runtime.h>
#include <stdint.h>

#define T_DIM 2048
#define B_DIM 16
#define H_DIM 1024
#define M_DIM (T_DIM * B_DIM)   // 32768 rows
#define TCHUNK 32

typedef __attribute__((ext_vector_type(8))) short bf16x8;
typedef __attribute__((ext_vector_type(4))) float floatx4;

#define BARRIER() asm volatile("s_barrier" ::: "memory")
#define LGKM0()                                            \
  do {                                                     \
    asm volatile("s_waitcnt lgkmcnt(0)" ::: "memory");     \
    __builtin_amdgcn_sched_barrier(0);                     \
  } while (0)

__device__ inline unsigned short f2bf(float f) {
  union { float f; unsigned int u; } c; c.f = f;
  unsigned int u = c.u;
  return (unsigned short)((u + 0x7FFFu + ((u >> 16) & 1u)) >> 16);  // RNE
}

__device__ inline float bf2f(unsigned short u) {
  union { float f; unsigned int u; } c; c.u = ((unsigned int)u) << 16;
  return c.f;
}

__device__ inline float fast_tanh(float x) {
  float e = __expf(2.0f * x);
  return 1.0f - 2.0f / (e + 1.0f);
}

__device__ __forceinline__ void glds16(const unsigned short* g,
                                       const unsigned short* l) {
  __builtin_amdgcn_global_load_lds(
      (const __attribute__((address_space(1))) void*)g,
      (__attribute__((address_space(3))) void*)l, 16, 0, 0);
}

// ---------------- X fp32 -> bf16 ----------------
__global__ void convert_x_kernel(const float* __restrict__ x,
                                 unsigned short* __restrict__ xb) {
  size_t i = ((size_t)blockIdx.x * 256 + threadIdx.x) * 4;
  float4 v = *(const float4*)(x + i);
  ushort4 o;
  o.x = f2bf(v.x); o.y = f2bf(v.y); o.z = f2bf(v.z); o.w = f2bf(v.w);
  *(ushort4*)(xb + i) = o;
}

// ---------------- W[K][N] fp32 -> Wt[N][K] bf16 ----------------
__global__ void transpose_w_kernel(const float* __restrict__ w,
                                   unsigned short* __restrict__ wt) {
  __shared__ float tile[32][33];
  int tx = threadIdx.x, ty = threadIdx.y;
  int n0 = blockIdx.x * 32, k0 = blockIdx.y * 32;
  for (int i = ty; i < 32; i += 8)
    tile[i][tx] = w[(size_t)(k0 + i) * H_DIM + n0 + tx];
  __syncthreads();
  for (int i = ty; i < 32; i += 8)
    wt[(size_t)(n0 + i) * H_DIM + k0 + tx] = f2bf(tile[tx][i]);
}

// ---------------- scores = tanh(X@W)@proj — 256x256 8-phase schedule ------
// BM=BN=256, BK=64, 512 threads = 8 waves (2M x 4N), per-wave 128x64 output.
// LDS 128 KiB: [2 dbuf][2 halves][128x64] for A and B, XOR-swizzled
// (pre-swizzled global source + swizzled ds_read; linear global_load_lds dst).
// Per K-tile: 4 phases {ds_read subtile | issue 1 half-tile prefetch |
// barrier | lgkmcnt(0) | setprio(1) 16xMFMA setprio(0) | barrier}, counted
// vmcnt(4) once per K-tile (2 half-tiles stay in flight across barriers).
// Half-tile order per tile: [Bh0,Bh1,Ah0,Ah1]; issue index h = 4t+6+p so each
// overwrite is barrier-ordered after the region's last reader phase.
// XCD swizzle: 4 N-splits of one 256-row A-slab land on the same XCD.
__global__ __launch_bounds__(512, 2)
void score_gemm_kernel(const unsigned short* __restrict__ Xb,
                       const unsigned short* __restrict__ Wt,
                       const float* __restrict__ proj,
                       float* __restrict__ scores) {
  __shared__ __align__(16) unsigned short ldsA[32768];   // 64 KiB
  __shared__ __align__(16) unsigned short ldsB[32768];   // 64 KiB

  const int tid  = threadIdx.x;
  const int lane = tid & 63;
  const int wave = tid >> 6;       // 0..7
  const int wy   = wave >> 2;      // 0..1 (M)
  const int wx   = wave & 3;       // 0..3 (N)
  const int quad = lane >> 4, l16 = lane & 15;

  const int idx   = blockIdx.x;
  const int x7    = idx & 7;
  const int split = (idx >> 3) & 3;
  const int g     = idx >> 5;
  const int bm    = g * 8 + x7;        // 0..127
  const int m0    = bm * 256;
  const int n0    = split * 256;

  // staging: per half-tile (128x64) each thread issues 2 x 16B loads.
  // LDS dst = wave-uniform base (+HW lane*16); global src is per-lane
  // pre-swizzled (granule cg = cs ^ (row&7)).
  int gOff0, gOff1, lB0, lB1;
  {
    int ci0 = wave * 64 + lane;
    int r0  = ci0 >> 3;
    gOff0 = r0 * H_DIM + (((ci0 & 7) ^ (r0 & 7)) * 8);
    lB0   = (wave * 64) * 8;
    int ci1 = ci0 + 512;
    int r1  = ci1 >> 3;
    gOff1 = r1 * H_DIM + (((ci1 & 7) ^ (r1 & 7)) * 8);
    lB1   = (wave * 64 + 512) * 8;
  }

  // ds-read swizzled granules (row&7 == l16&7 for all fragment rows)
  const int cg0 = quad ^ (l16 & 7);
  const int cg1 = (quad + 4) ^ (l16 & 7);

  // half-tile h: tile th = h>>2 (buf th&1), ht = h&3: 0=Bh0 1=Bh1 2=Ah0 3=Ah1
  auto issue_ht = [&](int h) {
    int th = h >> 2, ht = h & 3;
    int base = (th & 1) * 16384 + (ht & 1) * 8192;
    int k0 = th * 64;
    if (ht & 2) {
      const unsigned short* gs =
          Xb + (size_t)(m0 + (ht & 1) * 128) * H_DIM + k0;
      glds16(gs + gOff0, &ldsA[base + lB0]);
      glds16(gs + gOff1, &ldsA[base + lB1]);
    } else {
      const unsigned short* gs =
          Wt + (size_t)(n0 + (ht & 1) * 128) * H_DIM + k0;
      glds16(gs + gOff0, &ldsB[base + lB0]);
      glds16(gs + gOff1, &ldsB[base + lB1]);
    }
  };

  floatx4 acc[8][4];
  #pragma unroll
  for (int m = 0; m < 8; ++m)
    #pragma unroll
    for (int n = 0; n < 4; ++n) acc[m][n] = (floatx4){0.f, 0.f, 0.f, 0.f};

  // prologue: tile0 fully + tile1 Bh0,Bh1; wait so tile0 landed (4 newest
  // loads = h4,h5 may remain in flight)
  #pragma unroll
  for (int h = 0; h < 6; ++h) issue_ht(h);
  asm volatile("s_waitcnt vmcnt(4)" ::: "memory");
  BARRIER();

  int cur = 0;
  for (int t = 0; t < 16; ++t) {
    const int aB = cur * 16384 + wy * 8192;          // wave's A half
    const int bB = cur * 16384 + (wx >> 1) * 8192;   // wave's B half
    const int nL = (wx & 1) * 64;                    // wave's n-base in half

    bf16x8 af[4][2], bfr[2][2][2];

    // ---- phase 0: (mq0, nq0) — read A[mq0](8) + B[nq0](4) ----
    #pragma unroll
    for (int rs = 0; rs < 4; ++rs) {
      int r = rs * 16 + l16;
      af[rs][0] = *(const bf16x8*)&ldsA[aB + r * 64 + cg0 * 8];
      af[rs][1] = *(const bf16x8*)&ldsA[aB + r * 64 + cg1 * 8];
    }
    #pragma unroll
    for (int ns = 0; ns < 2; ++ns) {
      int n = nL + ns * 16 + l16;
      bfr[0][ns][0] = *(const bf16x8*)&ldsB[bB + n * 64 + cg0 * 8];
      bfr[0][ns][1] = *(const bf16x8*)&ldsB[bB + n * 64 + cg1 * 8];
    }
    { int h = 4 * t + 6; if (h < 64) issue_ht(h); }   // t+1.Ah0 (other buf)
    BARRIER();
    LGKM0();
    __builtin_amdgcn_s_setprio(1);
    #pragma unroll
    for (int k = 0; k < 2; ++k)
      #pragma unroll
      for (int rs = 0; rs < 4; ++rs)
        #pragma unroll
        for (int ns = 0; ns < 2; ++ns)
          acc[rs][ns] = __builtin_amdgcn_mfma_f32_16x16x32_bf16(
              af[rs][k], bfr[0][ns][k], acc[rs][ns], 0, 0, 0);
    __builtin_amdgcn_s_setprio(0);
    BARRIER();

    // ---- phase 1: (mq0, nq1) — read B[nq1](4) ----
    #pragma unroll
    for (int ns = 0; ns < 2; ++ns) {
      int n = nL + 32 + ns * 16 + l16;
      bfr[1][ns][0] = *(const bf16x8*)&ldsB[bB + n * 64 + cg0 * 8];
      bfr[1][ns][1] = *(const bf16x8*)&ldsB[bB + n * 64 + cg1 * 8];
    }
    { int h = 4 * t + 7; if (h < 64) issue_ht(h); }   // t+1.Ah1 (other buf)
    BARRIER();
    LGKM0();
    __builtin_amdgcn_s_setprio(1);
    #pragma unroll
    for (int k = 0; k < 2; ++k)
      #pragma unroll
      for (int rs = 0; rs < 4; ++rs)
        #pragma unroll
        for (int ns = 0; ns < 2; ++ns)
          acc[rs][2 + ns] = __builtin_amdgcn_mfma_f32_16x16x32_bf16(
              af[rs][k], bfr[1][ns][k], acc[rs][2 + ns], 0, 0, 0);
    __builtin_amdgcn_s_setprio(0);
    BARRIER();

    // ---- phase 2: (mq1, nq1) — read A[mq1](8); B reads done for this buf,
    //      so t+2.Bh0 overwrite of cur buf is now safe ----
    #pragma unroll
    for (int rs = 0; rs < 4; ++rs) {
      int r = 64 + rs * 16 + l16;
      af[rs][0] = *(const bf16x8*)&ldsA[aB + r * 64 + cg0 * 8];
      af[rs][1] = *(const bf16x8*)&ldsA[aB + r * 64 + cg1 * 8];
    }
    { int h = 4 * t + 8; if (h < 64) issue_ht(h); }   // t+2.Bh0 (cur buf)
    BARRIER();
    LGKM0();
    __builtin_amdgcn_s_setprio(1);
    #pragma unroll
    for (int k = 0; k < 2; ++k)
      #pragma unroll
      for (int rs = 0; rs < 4; ++rs)
        #pragma unroll
        for (int ns = 0; ns < 2; ++ns)
          acc[4 + rs][2 + ns] = __builtin_amdgcn_mfma_f32_16x16x32_bf16(
              af[rs][k], bfr[1][ns][k], acc[4 + rs][2 + ns], 0, 0, 0);
    __builtin_amdgcn_s_setprio(0);
    BARRIER();

    // ---- phase 3: (mq1, nq0) — registers only ----
    { int h = 4 * t + 9; if (h < 64) issue_ht(h); }   // t+2.Bh1 (cur buf)
    BARRIER();
    LGKM0();
    __builtin_amdgcn_s_setprio(1);
    #pragma unroll
    for (int k = 0; k < 2; ++k)
      #pragma unroll
      for (int rs = 0; rs < 4; ++rs)
        #pragma unroll
        for (int ns = 0; ns < 2; ++ns)
          acc[4 + rs][ns] = __builtin_amdgcn_mfma_f32_16x16x32_bf16(
              af[rs][k], bfr[0][ns][k], acc[4 + rs][ns], 0, 0, 0);
    __builtin_amdgcn_s_setprio(0);
    // counted vmcnt: next tile's 4 half-tiles done; 2 newest half-tiles
    // (4 loads) stay in flight. Drain fully before the last tile.
    if (t < 14) asm volatile("s_waitcnt vmcnt(4)" ::: "memory");
    else        asm volatile("s_waitcnt vmcnt(0)" ::: "memory");
    BARRIER();

    cur ^= 1;
  }

  // ---- epilogue: sc[row] += tanh(acc) . proj, 16-lane reduce, atomic ----
  float pv[2][2];
  #pragma unroll
  for (int nq = 0; nq < 2; ++nq)
    #pragma unroll
    for (int ns = 0; ns < 2; ++ns)
      pv[nq][ns] = proj[n0 + wx * 64 + nq * 32 + ns * 16 + l16];

  #pragma unroll
  for (int m = 0; m < 8; ++m)
    #pragma unroll
    for (int gg = 0; gg < 4; ++gg) {
      float v = 0.f;
      #pragma unroll
      for (int nq = 0; nq < 2; ++nq)
        #pragma unroll
        for (int ns = 0; ns < 2; ++ns)
          v += fast_tanh(acc[m][nq * 2 + ns][gg]) * pv[nq][ns];
      v += __shfl_xor(v, 1);
      v += __shfl_xor(v, 2);
      v += __shfl_xor(v, 4);
      v += __shfl_xor(v, 8);
      if (l16 == 0) {
        int row = m0 + wy * 128 + (m >> 2) * 64 + (m & 3) * 16 + quad * 4 + gg;
        atomicAdd(&scores[row], v);
      }
    }
}

// ---------------- windowed softmax + weighted sum (bf16 taps) ----------------
__global__ void out_kernel_bf16(const float* __restrict__ x,
                                const unsigned short* __restrict__ xb,
                                const float* __restrict__ scores,
                                const int* __restrict__ wp,
                                float* __restrict__ out) {
  int w = *wp;
  int t0 = blockIdx.x * TCHUNK;
  int b  = blockIdx.y;
  int h  = threadIdx.x;                 // 4-element group within row
  const float4* x4 = (const float4*)x;
  float4* o4 = (float4*)out;
  const ushort4* xb4 = (const ushort4*)xb;

  if (w == 3) {
    float4 z = {0.f, 0.f, 0.f, 0.f};
    float4 a0, a1, a2;
    float  s0, s1, s2;
    #pragma unroll
    for (int j = 0; j < 3; ++j) {
      int tm = t0 - 3 + j;
      float4 a = z; float s = 0.f;
      if (tm >= 0) {
        ushort4 u = xb4[((size_t)tm * B_DIM + b) * 256 + h];
        a.x = bf2f(u.x); a.y = bf2f(u.y); a.z = bf2f(u.z); a.w = bf2f(u.w);
        s = scores[tm * B_DIM + b];
      }
      if (j == 0) { a0 = a; s0 = s; }
      else if (j == 1) { a1 = a; s1 = s; }
      else { a2 = a; s2 = s; }
    }
    for (int i = 0; i < TCHUNK; ++i) {
      int t = t0 + i;
      size_t rbase = ((size_t)t * B_DIM + b) * 256 + h;
      ushort4 u = xb4[rbase];
      float4 v;
      v.x = bf2f(u.x); v.y = bf2f(u.y); v.z = bf2f(u.z); v.w = bf2f(u.w);
      float sv = scores[t * B_DIM + b];
      if (t < 3) {
        o4[rbase] = x4[rbase];           // exact fp32 passthrough
      } else {
        float m = fmaxf(fmaxf(s0, s1), s2);
        float e0 = __expf(s0 - m), e1 = __expf(s1 - m), e2 = __expf(s2 - m);
        float inv = 1.0f / (e0 + e1 + e2);
        e0 *= inv; e1 *= inv; e2 *= inv;
        float4 o;
        o.x = e0 * a0.x + e1 * a1.x + e2 * a2.x;
        o.y = e0 * a0.y + e1 * a1.y + e2 * a2.y;
        o.z = e0 * a0.z + e1 * a1.z + e2 * a2.z;
        o.w = e0 * a0.w + e1 * a1.w + e2 * a2.w;
        o4[rbase] = o;
      }
      a0 = a1; a1 = a2; a2 = v;
      s0 = s1; s1 = s2; s2 = sv;
    }
  } else {
    if (w > 8) w = 8;
    for (int i = 0; i < TCHUNK; ++i) {
      int t = t0 + i;
      size_t rbase = ((size_t)t * B_DIM + b) * 256 + h;
      if (t < w) { o4[rbase] = x4[rbase]; continue; }
      float s[8];
      float mx = -1e30f;
      for (int j = 0; j < w; ++j) {
        s[j] = scores[(t - w + j) * B_DIM + b];
        mx = fmaxf(mx, s[j]);
      }
      float sum = 0.f;
      for (int j = 0; j < w; ++j) { s[j] = __expf(s[j] - mx); sum += s[j]; }
      float inv = 1.0f / sum;
      float4 o = {0.f, 0.f, 0.f, 0.f};
      for (int j = 0; j < w; ++j) {
        float a = s[j] * inv;
        float4 v = x4[((size_t)(t - w + j) * B_DIM + b) * 256 + h];
        o.x += a * v.x; o.y += a * v.y; o.z += a * v.z; o.w += a * v.w;
      }
      o4[rbase] = o;
    }
  }
}

// ---------------- fp32-tap fallback (Xb aliases d_out; can't read it here) --
__global__ void out_kernel_f32(const float* __restrict__ x,
                               const float* __restrict__ scores,
                               const int* __restrict__ wp,
                               float* __restrict__ out) {
  int w = *wp;
  int t0 = blockIdx.x * TCHUNK;
  int b  = blockIdx.y;
  int h  = threadIdx.x;
  const float4* x4 = (const float4*)x;
  float4* o4 = (float4*)out;

  if (w == 3) {
    float4 z = {0.f, 0.f, 0.f, 0.f};
    float4 a0, a1, a2;
    float  s0, s1, s2;
    {
      int tm = t0 - 3;
      a0 = (tm >= 0) ? x4[((size_t)tm * B_DIM + b) * 256 + h] : z;
      s0 = (tm >= 0) ? scores[tm * B_DIM + b] : 0.f;
      tm = t0 - 2;
      a1 = (tm >= 0) ? x4[((size_t)tm * B_DIM + b) * 256 + h] : z;
      s1 = (tm >= 0) ? scores[tm * B_DIM + b] : 0.f;
      tm = t0 - 1;
      a2 = (tm >= 0) ? x4[((size_t)tm * B_DIM + b) * 256 + h] : z;
      s2 = (tm >= 0) ? scores[tm * B_DIM + b] : 0.f;
    }
    for (int i = 0; i < TCHUNK; ++i) {
      int t = t0 + i;
      size_t rbase = ((size_t)t * B_DIM + b) * 256 + h;
      float4 v = x4[rbase];
      float  sv = scores[t * B_DIM + b];
      if (t < 3) {
        o4[rbase] = v;
      } else {
        float m = fmaxf(fmaxf(s0, s1), s2);
        float e0 = __expf(s0 - m), e1 = __expf(s1 - m), e2 = __expf(s2 - m);
        float inv = 1.0f / (e0 + e1 + e2);
        e0 *= inv; e1 *= inv; e2 *= inv;
        float4 o;
        o.x = e0 * a0.x + e1 * a1.x + e2 * a2.x;
        o.y = e0 * a0.y + e1 * a1.y + e2 * a2.y;
        o.z = e0 * a0.z + e1 * a1.z + e2 * a2.z;
        o.w = e0 * a0.w + e1 * a1.w + e2 * a2.w;
        o4[rbase] = o;
      }
      a0 = a1; a1 = a2; a2 = v;
      s0 = s1; s1 = s2; s2 = sv;
    }
  } else {
    if (w > 8) w = 8;
    for (int i = 0; i < TCHUNK; ++i) {
      int t = t0 + i;
      size_t rbase = ((size_t)t * B_DIM + b) * 256 + h;
      if (t < w) { o4[rbase] = x4[rbase]; continue; }
      float s[8];
      float mx = -1e30f;
      for (int j = 0; j < w; ++j) {
        s[j] = scores[(t - w + j) * B_DIM + b];
        mx = fmaxf(mx, s[j]);
      }
      float sum = 0.f;
      for (int j = 0; j < w; ++j) { s[j] = __expf(s[j] - mx); sum += s[j]; }
      float inv = 1.0f / sum;
      float4 o = {0.f, 0.f, 0.f, 0.f};
      for (int j = 0; j < w; ++j) {
        float a = s[j] * inv;
        float4 v = x4[((size_t)(t - w + j) * B_DIM + b) * 256 + h];
        o.x += a * v.x; o.y += a * v.y; o.z += a * v.z; o.w += a * v.w;
      }
      o4[rbase] = o;
    }
  }
}

extern "C" void kernel_launch(void* const* d_in, const int* in_sizes, int n_in,
                              void* d_out, int out_size, void* d_ws, size_t ws_size,
                              hipStream_t stream) {
  const float* x    = (const float*)d_in[0];
  const float* w    = (const float*)d_in[1];
  const float* proj = (const float*)d_in[2];
  const int*   wp   = (const int*)d_in[3];
  float* out = (float*)d_out;

  const size_t XB_BYTES = (size_t)64 * 1024 * 1024;
  const size_t WT_BYTES = (size_t)2 * 1024 * 1024;
  const size_t need = XB_BYTES + WT_BYTES + (size_t)M_DIM * sizeof(float);
  const bool use_ws = ws_size >= need;

  unsigned short* Xb;
  unsigned short* Wt;
  float* scores;
  if (use_ws) {
    Xb = (unsigned short*)d_ws;
    Wt = (unsigned short*)((char*)d_ws + XB_BYTES);
    scores = (float*)((char*)d_ws + XB_BYTES + WT_BYTES);
  } else {
    Xb = (unsigned short*)d_out;
    Wt = (unsigned short*)((char*)d_out + XB_BYTES);
    scores = (float*)d_ws;
  }

  hipMemsetAsync(scores, 0, M_DIM * sizeof(float), stream);

  convert_x_kernel<<<M_DIM * H_DIM / 1024, 256, 0, stream>>>(x, Xb);
  transpose_w_kernel<<<dim3(32, 32), dim3(32, 8), 0, stream>>>(w, Wt);
  score_gemm_kernel<<<512, 512, 0, stream>>>(Xb, Wt, proj, scores);
  if (use_ws)
    out_kernel_bf16<<<dim3(T_DIM / TCHUNK, B_DIM), 256, 0, stream>>>(x, Xb, scores, wp, out);
  else
    out_kernel_f32<<<dim3(T_DIM / TCHUNK, B_DIM), 256, 0, stream>>>(x, scores, wp, out);
}